// Round 1
// 667.396 us; speedup vs baseline: 1.2078x; 1.2078x over previous
//
#include <hip/hip_runtime.h>
#include <hip/hip_bf16.h>
#include <cstdint>
#include <cstddef>

typedef __hip_bfloat16 bf16;
typedef short bf16x8 __attribute__((ext_vector_type(8)));
typedef float f32x4 __attribute__((ext_vector_type(4)));

#define MFMA(a, b, c) __builtin_amdgcn_mfma_f32_16x16x32_bf16((a), (b), (c), 0, 0, 0)

// ---------------------------------------------------------------------------
// K0: transpose weights f32 -> bf16: dst[n*K+k] = src[k*N+n]
// ---------------------------------------------------------------------------
__global__ __launch_bounds__(256) void transpose_k(const float* __restrict__ src,
                                                   bf16* __restrict__ dst, int K, int N) {
  int idx = blockIdx.x * 256 + threadIdx.x;
  if (idx >= K * N) return;
  int n = idx / K, k = idx - n * K;
  dst[idx] = __float2bfloat16(src[k * N + n]);
}

// ---------------------------------------------------------------------------
// K1: depthwise 3x3 conv (SAME) fused with window gather (f32 in, bf16 out).
// Thread = channel; halo kept in a 3-row rolling REGISTER buffer (no LDS!).
// Loads are float4-vectorized along w (rows are 4-aligned at w0); the two
// edge columns are masked scalars with wave-uniform predicates.
// ---------------------------------------------------------------------------
__global__ __launch_bounds__(256) void conv_gather_k(const float* __restrict__ kvf,
                                                     const float* __restrict__ wdw,
                                                     bf16* __restrict__ kvw,
                                                     int wid_base, int nw) {
  int bid = blockIdx.x;
  int sw = (bid & 7) * (nw >> 3) + (bid >> 3);
  int wid = wid_base + sw;
  int b = wid >> 10, rem = wid & 1023, wh = rem >> 5, ww = rem & 31;
  int h0 = wh * 8, w0 = ww * 8;
  int c = threadIdx.x;
  const float* src = kvf + ((size_t)(b * 256 + c) << 16) + w0;
  float wr[9];
#pragma unroll
  for (int q = 0; q < 9; ++q) wr[q] = wdw[c * 9 + q];
  const bool wlo = (w0 > 0), whi = (w0 < 248);  // wave-uniform edge masks

  float rows[3][10];
  auto load_row = [&](int gh, float* r) {
    if (gh >= 0 && gh < 256) {  // wave-uniform
      const float* rp = src + gh * 256;
      r[0] = wlo ? rp[-1] : 0.f;
      f32x4 a4 = *(const f32x4*)&rp[0];
      f32x4 b4 = *(const f32x4*)&rp[4];
#pragma unroll
      for (int e = 0; e < 4; ++e) {
        r[1 + e] = a4[e];
        r[5 + e] = b4[e];
      }
      r[9] = whi ? rp[8] : 0.f;
    } else {
#pragma unroll
      for (int e = 0; e < 10; ++e) r[e] = 0.f;
    }
  };

  load_row(h0 - 1, rows[0]);
  load_row(h0, rows[1]);
#pragma unroll
  for (int i = 0; i < 8; ++i) {
    load_row(h0 + i + 1, rows[(i + 2) % 3]);  // static index after unroll
#pragma unroll
    for (int j = 0; j < 8; ++j) {
      float acc = 0.f;
#pragma unroll
      for (int di = 0; di < 3; ++di) {
        const float* rp = rows[(i + di) % 3];
        acc = __builtin_fmaf(wr[di * 3 + 0], rp[j], acc);
        acc = __builtin_fmaf(wr[di * 3 + 1], rp[j + 1], acc);
        acc = __builtin_fmaf(wr[di * 3 + 2], rp[j + 2], acc);
      }
      kvw[((size_t)(sw * 64 + i * 8 + j) << 8) + c] = __float2bfloat16(acc);
    }
  }
}

// ---------------------------------------------------------------------------
// K2: kv projection GEMM per window: [64x256] @ wkvT -> k_s[t][c], vT_s[d][t]
// ---------------------------------------------------------------------------
__global__ __launch_bounds__(256) void kv_gemm_k(const bf16* __restrict__ kvw,
                                                 const bf16* __restrict__ wkvT,
                                                 const float* __restrict__ bkv,
                                                 bf16* __restrict__ k_s,
                                                 bf16* __restrict__ vT_s,
                                                 int wid_base, int nw) {
  __shared__ __align__(16) bf16 X[64 * 264];
  int bid = blockIdx.x;
  int sw = (bid & 7) * (nw >> 3) + (bid >> 3);
  int tid = threadIdx.x;
  {  // stage A (contiguous copy, vectorized)
    int t = tid >> 2, cb = (tid & 3) * 64;
    const bf16* src = &kvw[((size_t)(sw * 64 + t) << 8) + cb];
    bf16* dst = &X[t * 264 + cb];
    for (int i = 0; i < 8; ++i) *(bf16x8*)&dst[i * 8] = *(const bf16x8*)&src[i * 8];
  }
  __syncthreads();
  int wave = tid >> 6, lane = tid & 63, quad = lane >> 4, l16 = lane & 15;
  int n0 = wave * 128;
  f32x4 zero4 = {0.f, 0.f, 0.f, 0.f};
  f32x4 acc[4][8];
  for (int mt = 0; mt < 4; ++mt)
    for (int nt = 0; nt < 8; ++nt) acc[mt][nt] = zero4;
  for (int k0 = 0; k0 < 256; k0 += 32) {
    bf16x8 a[4], bb[8];
    for (int mt = 0; mt < 4; ++mt)
      a[mt] = *(const bf16x8*)&X[(mt * 16 + l16) * 264 + k0 + quad * 8];
    for (int nt = 0; nt < 8; ++nt)
      bb[nt] = *(const bf16x8*)&wkvT[(size_t)(n0 + nt * 16 + l16) * 256 + k0 + quad * 8];
    for (int mt = 0; mt < 4; ++mt)
      for (int nt = 0; nt < 8; ++nt) acc[mt][nt] = MFMA(a[mt], bb[nt], acc[mt][nt]);
  }
  __syncthreads();  // everyone done reading X; waves 2,3 will reuse it for v
  for (int nt = 0; nt < 8; ++nt) {
    int n = n0 + nt * 16 + l16;
    float bias = bkv[n];
    if (n < 256) {  // wave-uniform branch (waves 0,1)
      for (int mt = 0; mt < 4; ++mt) {
        int mb = mt * 16 + quad * 4;
        for (int r = 0; r < 4; ++r)
          k_s[((size_t)(sw * 64 + mb + r) << 8) + n] =
              __float2bfloat16(acc[mt][nt][r] + bias);
      }
    } else {  // waves 2,3: park v in LDS for transpose
      int d = n - 256;
      for (int mt = 0; mt < 4; ++mt) {
        int mb = mt * 16 + quad * 4;
        for (int r = 0; r < 4; ++r)
          X[(mb + r) * 264 + d] = __float2bfloat16(acc[mt][nt][r] + bias);
      }
    }
  }
  __syncthreads();
  {  // cooperative transposed write: vT_s[sw][d][t], contiguous in t
    int t = tid & 63, d0 = tid >> 6;
    for (int d = d0; d < 256; d += 4)
      vT_s[((size_t)(sw * 256 + d) << 6) + t] = X[t * 264 + d];
  }
}

// ---------------------------------------------------------------------------
// K3: q projection GEMM per window with fused NCHW gather; q = (x@wq+bq)*SCALE
// Gather is float4-vectorized along w (16 aligned loads/thread); LDS writes
// are lane=c contiguous (conflict-free).
// ---------------------------------------------------------------------------
__global__ __launch_bounds__(256) void q_gemm_k(const float* __restrict__ qf,
                                                const bf16* __restrict__ wqT,
                                                const float* __restrict__ bq,
                                                bf16* __restrict__ q_s,
                                                int wid_base, int nw) {
  __shared__ __align__(16) bf16 X[64 * 264];
  int bid = blockIdx.x;
  int sw = (bid & 7) * (nw >> 3) + (bid >> 3);
  int wid = wid_base + sw;
  int b = wid >> 10, rem = wid & 1023, wh = rem >> 5, ww = rem & 31;
  int h0 = wh * 8, w0 = ww * 8;
  int tid = threadIdx.x;
  {  // gather: thread = channel, float4 rows of the 8x8 window
    int c = tid;
    const float* src = qf + ((size_t)(b * 256 + c) << 16) + (size_t)h0 * 256 + w0;
#pragma unroll
    for (int i = 0; i < 8; ++i) {
      f32x4 a4 = *(const f32x4*)&src[i * 256];
      f32x4 b4 = *(const f32x4*)&src[i * 256 + 4];
#pragma unroll
      for (int e = 0; e < 4; ++e) {
        X[(i * 8 + e) * 264 + c] = __float2bfloat16(a4[e]);
        X[(i * 8 + 4 + e) * 264 + c] = __float2bfloat16(b4[e]);
      }
    }
  }
  __syncthreads();
  int wave = tid >> 6, lane = tid & 63, quad = lane >> 4, l16 = lane & 15;
  int n0 = wave * 64;
  f32x4 zero4 = {0.f, 0.f, 0.f, 0.f};
  f32x4 acc[4][4];
  for (int mt = 0; mt < 4; ++mt)
    for (int nt = 0; nt < 4; ++nt) acc[mt][nt] = zero4;
  for (int k0 = 0; k0 < 256; k0 += 32) {
    bf16x8 a[4], bb[4];
    for (int mt = 0; mt < 4; ++mt)
      a[mt] = *(const bf16x8*)&X[(mt * 16 + l16) * 264 + k0 + quad * 8];
    for (int nt = 0; nt < 4; ++nt)
      bb[nt] = *(const bf16x8*)&wqT[(size_t)(n0 + nt * 16 + l16) * 256 + k0 + quad * 8];
    for (int mt = 0; mt < 4; ++mt)
      for (int nt = 0; nt < 4; ++nt) acc[mt][nt] = MFMA(a[mt], bb[nt], acc[mt][nt]);
  }
  const float scale = 0.1767766952966369f;  // 32^-0.5
  for (int nt = 0; nt < 4; ++nt) {
    int n = n0 + nt * 16 + l16;
    float bias = bq[n];
    for (int mt = 0; mt < 4; ++mt) {
      int mb = mt * 16 + quad * 4;
      for (int r = 0; r < 4; ++r)
        q_s[((size_t)(sw * 64 + mb + r) << 8) + n] =
            __float2bfloat16((acc[mt][nt][r] + bias) * scale);
    }
  }
}

// ---------------------------------------------------------------------------
// K4: windowed attention. wave w handles heads {w, w+4}. a_out aliases k_s
// (no __restrict__ on those two!). Safe: each 32-col head block is
// read-then-written by exactly one wave, and hi=0 writes (cols 0..127) are
// disjoint from hi=1 reads (cols 128..255).
// ---------------------------------------------------------------------------
__global__ __launch_bounds__(256) void attn_k(const bf16* __restrict__ q_s,
                                              const bf16* k_s,
                                              const bf16* __restrict__ vT_s,
                                              bf16* a_out,
                                              int wid_base, int nw) {
  __shared__ __align__(16) bf16 P[4 * 64 * 72];
  int bid = blockIdx.x;
  int sw = (bid & 7) * (nw >> 3) + (bid >> 3);
  int tid = threadIdx.x, wave = tid >> 6, lane = tid & 63, quad = lane >> 4, l16 = lane & 15;
  const bf16* qw = q_s + ((size_t)sw << 14);
  const bf16* kw = k_s + ((size_t)sw << 14);
  const bf16* vw = vT_s + ((size_t)sw << 14);
  bf16* ow = a_out + ((size_t)sw << 14);
  bf16* Pw = P + wave * 64 * 72;
  f32x4 zero4 = {0.f, 0.f, 0.f, 0.f};
  for (int hi = 0; hi < 2; ++hi) {
    int co = (wave + hi * 4) * 32;  // head channel offset
    // S = q @ k^T  (q already scaled); K = 32 = one MFMA k-step
    f32x4 s[4][4];
    for (int mt = 0; mt < 4; ++mt)
      for (int nt = 0; nt < 4; ++nt) s[mt][nt] = zero4;
    {
      bf16x8 a[4], bb[4];
      for (int mt = 0; mt < 4; ++mt)
        a[mt] = *(const bf16x8*)&qw[(size_t)(mt * 16 + l16) * 256 + co + quad * 8];
      for (int nt = 0; nt < 4; ++nt)
        bb[nt] = *(const bf16x8*)&kw[(size_t)(nt * 16 + l16) * 256 + co + quad * 8];
      for (int mt = 0; mt < 4; ++mt)
        for (int nt = 0; nt < 4; ++nt) s[mt][nt] = MFMA(a[mt], bb[nt], s[mt][nt]);
    }
    // softmax rows: row = mt*16 + quad*4 + r lives in the 16 lanes of a quad
    float rsum[4][4];
    for (int mt = 0; mt < 4; ++mt) {
      for (int r = 0; r < 4; ++r) {
        float m = s[mt][0][r];
        for (int nt = 1; nt < 4; ++nt) m = fmaxf(m, s[mt][nt][r]);
        m = fmaxf(m, __shfl_xor(m, 1, 64));
        m = fmaxf(m, __shfl_xor(m, 2, 64));
        m = fmaxf(m, __shfl_xor(m, 4, 64));
        m = fmaxf(m, __shfl_xor(m, 8, 64));
        float sum = 0.f;
        for (int nt = 0; nt < 4; ++nt) {
          float e = __expf(s[mt][nt][r] - m);
          s[mt][nt][r] = e;
          sum += e;
        }
        sum += __shfl_xor(sum, 1, 64);
        sum += __shfl_xor(sum, 2, 64);
        sum += __shfl_xor(sum, 4, 64);
        sum += __shfl_xor(sum, 8, 64);
        rsum[mt][r] = sum;  // rows match O's D-layout rows exactly
      }
    }
    // P (unnormalized, <=1) -> LDS in [row][col] so PV A-frags are b128 reads
    for (int mt = 0; mt < 4; ++mt)
      for (int nt = 0; nt < 4; ++nt)
        for (int r = 0; r < 4; ++r)
          Pw[(mt * 16 + quad * 4 + r) * 72 + nt * 16 + l16] =
              __float2bfloat16(s[mt][nt][r]);
    __syncthreads();
    // O = P @ V ; V from vT_s[d][t] so B-frags are contiguous
    f32x4 o[4][2];
    for (int mt = 0; mt < 4; ++mt)
      for (int nt = 0; nt < 2; ++nt) o[mt][nt] = zero4;
    for (int kk = 0; kk < 64; kk += 32) {
      bf16x8 pa[4], vb[2];
      for (int mt = 0; mt < 4; ++mt)
        pa[mt] = *(const bf16x8*)&Pw[(mt * 16 + l16) * 72 + kk + quad * 8];
      for (int nt = 0; nt < 2; ++nt)
        vb[nt] = *(const bf16x8*)&vw[(size_t)(co + nt * 16 + l16) * 64 + kk + quad * 8];
      for (int mt = 0; mt < 4; ++mt)
        for (int nt = 0; nt < 2; ++nt) o[mt][nt] = MFMA(pa[mt], vb[nt], o[mt][nt]);
    }
    for (int mt = 0; mt < 4; ++mt) {
      int mb = mt * 16 + quad * 4;
      for (int nt = 0; nt < 2; ++nt)
        for (int r = 0; r < 4; ++r)
          ow[((size_t)(mb + r) << 8) + co + nt * 16 + l16] =
              __float2bfloat16(o[mt][nt][r] / rsum[mt][r]);
    }
    __syncthreads();
  }
}

// ---------------------------------------------------------------------------
// K5: out projection + window-reverse scatter to NCHW, f32 output.
// D-layout rows mb..mb+3 are 4 consecutive w positions -> one float4 store
// per (mt,nt) per lane. No LDS needed.
// ---------------------------------------------------------------------------
__global__ __launch_bounds__(256) void oproj_k(const bf16* __restrict__ a_out,
                                               const bf16* __restrict__ wpT,
                                               const float* __restrict__ bp,
                                               float* __restrict__ out,
                                               int wid_base, int nw) {
  int bid = blockIdx.x;
  int sw = (bid & 7) * (nw >> 3) + (bid >> 3);
  int wid = wid_base + sw;
  int b = wid >> 10, rem = wid & 1023, wh = rem >> 5, ww = rem & 31;
  int h0 = wh * 8, w0 = ww * 8;
  int tid = threadIdx.x, wave = tid >> 6, lane = tid & 63, quad = lane >> 4, l16 = lane & 15;
  const bf16* aw = a_out + ((size_t)sw << 14);
  int n0 = wave * 64;
  f32x4 zero4 = {0.f, 0.f, 0.f, 0.f};
  f32x4 acc[4][4];
  for (int mt = 0; mt < 4; ++mt)
    for (int nt = 0; nt < 4; ++nt) acc[mt][nt] = zero4;
  for (int k0 = 0; k0 < 256; k0 += 32) {
    bf16x8 a[4], bb[4];
    for (int mt = 0; mt < 4; ++mt)
      a[mt] = *(const bf16x8*)&aw[(size_t)(mt * 16 + l16) * 256 + k0 + quad * 8];
    for (int nt = 0; nt < 4; ++nt)
      bb[nt] = *(const bf16x8*)&wpT[(size_t)(n0 + nt * 16 + l16) * 256 + k0 + quad * 8];
    for (int mt = 0; mt < 4; ++mt)
      for (int nt = 0; nt < 4; ++nt) acc[mt][nt] = MFMA(a[mt], bb[nt], acc[mt][nt]);
  }
  for (int nt = 0; nt < 4; ++nt) {
    int n = n0 + nt * 16 + l16;
    float bias = bp[n];
    float* chan = out + ((size_t)(b * 256 + n) << 16);
    for (int mt = 0; mt < 4; ++mt) {
      int row_i = mt * 2 + (quad >> 1);       // token>>3
      int j0 = (quad & 1) * 4;                // token&7 base
      f32x4 v4;
      for (int r = 0; r < 4; ++r) v4[r] = acc[mt][nt][r] + bias;
      *(f32x4*)&chan[(size_t)(h0 + row_i) * 256 + w0 + j0] = v4;
    }
  }
}

// ---------------------------------------------------------------------------
extern "C" void kernel_launch(void* const* d_in, const int* in_sizes, int n_in,
                              void* d_out, int out_size, void* d_ws, size_t ws_size,
                              hipStream_t stream) {
  const float* qf  = (const float*)d_in[0];
  const float* kvf = (const float*)d_in[1];
  const float* wdw = (const float*)d_in[2];
  const float* wq  = (const float*)d_in[3];
  const float* bq  = (const float*)d_in[4];
  const float* wkv = (const float*)d_in[5];
  const float* bkv = (const float*)d_in[6];
  const float* wp  = (const float*)d_in[7];
  const float* bp  = (const float*)d_in[8];
  float* out = (float*)d_out;

  bf16* wqT  = (bf16*)d_ws;
  bf16* wkvT = wqT + 256 * 256;
  bf16* wpT  = wkvT + 256 * 512;
  bf16* bufs = wpT + 256 * 256;
  size_t wbytes = (size_t)(256 * 256 + 256 * 512 + 256 * 256) * sizeof(bf16);
  size_t remb = ws_size > wbytes ? ws_size - wbytes : 0;
  int passes = 1;  // multi-pass fallback if workspace < ~201 MB
  while (passes < 32 && (size_t)3 * (2048 / passes) * 64 * 256 * 2 > remb) passes <<= 1;
  int nw = 2048 / passes;
  size_t sz = (size_t)nw * 64 * 256;
  bf16* R0 = bufs;      // kvw, then q (kvw dead after kv_gemm)
  bf16* R1 = R0 + sz;   // k, then attn-out (alias is per-wave-column safe)
  bf16* R2 = R1 + sz;   // vT

  transpose_k<<<256, 256, 0, stream>>>(wq, wqT, 256, 256);
  transpose_k<<<512, 256, 0, stream>>>(wkv, wkvT, 256, 512);
  transpose_k<<<256, 256, 0, stream>>>(wp, wpT, 256, 256);

  for (int p = 0; p < passes; ++p) {
    int wb = p * nw;
    conv_gather_k<<<nw, 256, 0, stream>>>(kvf, wdw, R0, wb, nw);
    kv_gemm_k<<<nw, 256, 0, stream>>>(R0, wkvT, bkv, R1, R2, wb, nw);
    q_gemm_k<<<nw, 256, 0, stream>>>(qf, wqT, bq, R0, wb, nw);
    attn_k<<<nw, 256, 0, stream>>>(R0, R1, R2, R1, wb, nw);
    oproj_k<<<nw, 256, 0, stream>>>(R1, wpT, bp, out, wb, nw);
  }
}